// Round 8
// baseline (776.230 us; speedup 1.0000x reference)
//
#include <hip/hip_runtime.h>
#include <hip/hip_bf16.h>

#define N_NODES 50000
#define N_EDGES 800000
#define DIM 128
#define HID 256
#define N_GRAPH 512
#define N_LAYER 3
#define EFEAT 8
#define BN_EPS 1e-5f
#define MAX_GROUPS 240000   // >= sum(ceil(deg/4)) <= (E + 3N)/4 = 237500
#define AGGR_WAVES 8192
#define SCAN_BLOCKS ((N_NODES + 1023) / 1024)

typedef unsigned short u16;
typedef unsigned int u32;

using bf16x8_t = short __attribute__((ext_vector_type(8)));
using f32x4_t  = float __attribute__((ext_vector_type(4)));
using f32x2    = float __attribute__((ext_vector_type(2)));
using f32x4v   = float __attribute__((ext_vector_type(4)));

// ---------------------------------------------------------------- utilities

__device__ __forceinline__ void atomic_add_f(float* p, float v) {
    unsafeAtomicAdd(p, v);
}
__device__ __forceinline__ u16 f2bf(float x) {
    union { float f; u32 u; } v; v.f = x;
    u32 r = v.u + 0x7FFF + ((v.u >> 16) & 1);
    return (u16)(r >> 16);
}
__device__ __forceinline__ float bf2f(u16 u) {
    union { u32 i; float f; } v; v.i = (u32)u << 16; return v.f;
}
__device__ __forceinline__ float2 up2(u32 p) {
    return make_float2(bf2f((u16)(p & 0xFFFF)), bf2f((u16)(p >> 16)));
}
__device__ __forceinline__ u32 pk2(float a, float b) {
    return (u32)f2bf(a) | ((u32)f2bf(b) << 16);
}
__device__ __forceinline__ f32x2 up2p(u32 p) {
    union { u32 u[2]; f32x2 f; } v;
    v.u[0] = p << 16;
    v.u[1] = p & 0xFFFF0000u;
    return v.f;
}
__device__ __forceinline__ f32x2 splat2(float x) {
    f32x2 r; r.x = x; r.y = x; return r;
}

// ---------------------------------------------------------------- weight transpose+convert to bf16
__global__ __launch_bounds__(256) void wconv_kernel(
    const float* __restrict__ W1, const float* __restrict__ W2,
    u16* __restrict__ W1t, u16* __restrict__ W2t)
{
    int idx = blockIdx.x * 256 + threadIdx.x;
    if (idx >= 6 * 32768) return;
    int m = idx >> 15;
    int off = idx & 32767;
    int l = m >> 1;
    if ((m & 1) == 0) {
        int r = off >> 8, c = off & 255;
        W1t[(size_t)l * 32768 + c * 128 + r] = f2bf(W1[(size_t)l * 32768 + r * 256 + c]);
    } else {
        int r = off >> 7, c = off & 127;
        W2t[(size_t)l * 32768 + c * 256 + r] = f2bf(W2[(size_t)l * 32768 + r * 128 + c]);
    }
}

// ---------------------------------------------------------------- CSR build
// Pass 1: histogram AND per-edge rank within its dst segment (atomicAdd return).
__global__ __launch_bounds__(256) void hist_rank_kernel(
    const int* __restrict__ ei, int* __restrict__ deg, int* __restrict__ rank)
{
    int e = blockIdx.x * 256 + threadIdx.x;
    if (e >= N_EDGES) return;
    int dst = ei[N_EDGES + e];
    rank[e] = atomicAdd(&deg[dst], 1);
}

// ---- multi-block scan over ceil(deg/4) (3 phases, all parallel) ----
__global__ __launch_bounds__(1024) void scan1_kernel(
    const int* __restrict__ deg, int* __restrict__ grpptr, int* __restrict__ bsum)
{
    __shared__ int wsum[16];
    int blk = blockIdx.x, tid = threadIdx.x;
    int i = blk * 1024 + tid;
    int v = (i < N_NODES) ? ((deg[i] + 3) >> 2) : 0;
    int lane = tid & 63, w = tid >> 6;
    int s = v;
    #pragma unroll
    for (int d = 1; d < 64; d <<= 1) { int t = __shfl_up(s, d); if (lane >= d) s += t; }
    if (lane == 63) wsum[w] = s;
    __syncthreads();
    if (tid < 64) {
        int t = (tid < 16) ? wsum[tid] : 0;
        #pragma unroll
        for (int d = 1; d < 16; d <<= 1) { int u = __shfl_up(t, d); if (tid >= d) t += u; }
        if (tid < 16) wsum[tid] = t;
    }
    __syncthreads();
    int excl = (w > 0) ? wsum[w - 1] : 0;
    int incl = s + excl;
    if (i < N_NODES) grpptr[i + 1] = incl;
    if (tid == 1023) bsum[blk] = incl;
}

__global__ __launch_bounds__(64) void scan2_kernel(int* __restrict__ bsum) {
    int tid = threadIdx.x;
    int v = (tid < SCAN_BLOCKS) ? bsum[tid] : 0;
    int s = v;
    #pragma unroll
    for (int d = 1; d < 64; d <<= 1) { int t = __shfl_up(s, d); if (tid >= d) s += t; }
    if (tid < SCAN_BLOCKS) bsum[tid] = s - v;   // exclusive
}

__global__ __launch_bounds__(1024) void scan3_kernel(
    int* __restrict__ grpptr, const int* __restrict__ bsum)
{
    int blk = blockIdx.x;
    int i = blk * 1024 + threadIdx.x;
    if (i < N_NODES) grpptr[i + 1] += bsum[blk];
    if (blk == 0 && threadIdx.x == 0) grpptr[0] = 0;
}

// init every 8B slot of the compact rec: {so=sentinel row, eaOff=0} x2 per uint4.
// Also fills the sentinel h_in row (bf16 -3.39e38) from block 0.
__global__ __launch_bounds__(256) void padinit_kernel(
    uint4* __restrict__ rec4, int nq, u16* __restrict__ hin)
{
    int i = blockIdx.x * 256 + threadIdx.x;
    if (blockIdx.x == 0 && threadIdx.x < 64)
        *(u32*)(hin + (size_t)N_NODES * DIM + threadIdx.x * 2) = 0xFF7FFF7Fu;
    if (i >= nq) return;
    u32 s = (u32)N_NODES << 8;
    rec4[i] = make_uint4(s, 0u, s, 0u);
}

// Pass 2 (NO atomics): one uint2 store per edge: {src row byte off, ea byte off}.
__global__ __launch_bounds__(256) void scatter_kernel(
    const int* __restrict__ ei,
    const int* __restrict__ rank, const int* __restrict__ grpptr,
    uint2* __restrict__ srec)
{
    int e = blockIdx.x * 256 + threadIdx.x;
    if (e >= N_EDGES) return;
    int src = __builtin_nontemporal_load(ei + e);
    int dst = __builtin_nontemporal_load(ei + N_EDGES + e);
    int rk  = __builtin_nontemporal_load(rank + e);
    int slot = (grpptr[dst] + (rk >> 2)) * 4 + (rk & 3);
    uint2 v;
    v.x = (u32)src << 8;        // hin row byte offset (DIM*2 = 256B rows)
    v.y = (u32)e << 5;          // edge_attr byte offset (EFEAT*4 = 32B rows)
    srec[slot] = v;
}

// Pass 3: expand compact records into 144B inline-attr groups.
__global__ __launch_bounds__(256) void expand_kernel(
    const uint2* __restrict__ srec, const float* __restrict__ ea,
    char* __restrict__ brec, int nslots)
{
    int i = blockIdx.x * 256 + threadIdx.x;
    if (i >= nslots) return;
    int g = i >> 2;
    int j = i & 3;
    uint2 v = srec[i];
    const char* eaB = (const char*)ea;
    f32x4v lo = *(const f32x4v*)(eaB + v.y);
    f32x4v hi = *(const f32x4v*)(eaB + v.y + 16);
    char* rb = brec + (size_t)g * 144;
    *(u32*)(rb + j * 4) = v.x;
    *(f32x4v*)(rb + 16 + j * 32) = lo;
    *(f32x4v*)(rb + 32 + j * 32) = hi;
}

// per-wave start node: balance by group count (binary search on grpptr)
__global__ __launch_bounds__(256) void wstart_kernel(
    const int* __restrict__ grpptr, int* __restrict__ wstart)
{
    int w = blockIdx.x * 256 + threadIdx.x;
    if (w > AGGR_WAVES) return;
    if (w == AGGR_WAVES) { wstart[w] = N_NODES; return; }
    int Gt = grpptr[N_NODES];
    int q = (int)(((long long)w * Gt) / AGGR_WAVES);
    int lo = 0, hi = N_NODES;
    while (lo < hi) { int mid = (lo + hi) >> 1; if (grpptr[mid] < q) lo = mid + 1; else hi = mid; }
    wstart[w] = lo;
}

// ---------------------------------------------------------------- h_in = act(src) + vn[batch]  (bf16 out)
template <bool USEBN, int VNM>
__global__ __launch_bounds__(256) void hin_kernel(
    const float* __restrict__ src,
    const float* __restrict__ sum2, const float* __restrict__ ss2,
    const float* __restrict__ g, const float* __restrict__ b, float invN,
    const int* __restrict__ batch,
    const float* __restrict__ vn_emb,
    const float* __restrict__ vnpre, const float* __restrict__ vsum, const float* __restrict__ vss,
    const float* __restrict__ gv, const float* __restrict__ btv, float invG,
    u16* __restrict__ hin, int total4)
{
    int idx = blockIdx.x * 256 + threadIdx.x;
    if (idx >= total4) return;
    int base = idx * 4;
    int n = base >> 7;
    int c = base & (DIM - 1);
    float4 v = *(const float4*)(src + base);
    float o[4] = {v.x, v.y, v.z, v.w};
    if (USEBN) {
        #pragma unroll
        for (int j = 0; j < 4; ++j) {
            int cj = c + j;
            float m = sum2[cj] * invN;
            float var = ss2[cj] * invN - m * m;
            float r = rsqrtf(var + BN_EPS);
            float a = g[cj] * r;
            o[j] = fmaxf(fmaf(a, o[j], b[cj] - m * a), 0.f);
        }
    }
    int grp = batch[n];
    if (VNM == 0) {
        const float4 w = *(const float4*)(vn_emb + c);
        o[0] += w.x; o[1] += w.y; o[2] += w.z; o[3] += w.w;
    } else {
        const float4 vp = *(const float4*)(vnpre + (size_t)grp * DIM + c);
        float vv[4] = {vp.x, vp.y, vp.z, vp.w};
        #pragma unroll
        for (int j = 0; j < 4; ++j) {
            int cj = c + j;
            float m = vsum[cj] * invG;
            float var = vss[cj] * invG - m * m;
            float r = rsqrtf(var + BN_EPS);
            float a = gv[cj] * r;
            o[j] += fmaxf(fmaf(a, vv[j], btv[cj] - m * a), 0.f);
        }
    }
    uint2 pk;
    pk.x = pk2(o[0], o[1]);
    pk.y = pk2(o[2], o[3]);
    *(uint2*)(hin + base) = pk;
}

// ---------------------------------------------------------------- gather aggregation
__device__ __forceinline__ void edge_term_f(
    u32 h, f32x4v ea, f32x4v eb, const f32x2* rW, f32x2 rB, f32x2& acc)
{
    f32x2 ex = rB;
    ex = __builtin_elementwise_fma(splat2(ea.x), rW[0], ex);
    ex = __builtin_elementwise_fma(splat2(ea.y), rW[1], ex);
    ex = __builtin_elementwise_fma(splat2(ea.z), rW[2], ex);
    ex = __builtin_elementwise_fma(splat2(ea.w), rW[3], ex);
    ex = __builtin_elementwise_fma(splat2(eb.x), rW[4], ex);
    ex = __builtin_elementwise_fma(splat2(eb.y), rW[5], ex);
    ex = __builtin_elementwise_fma(splat2(eb.z), rW[6], ex);
    ex = __builtin_elementwise_fma(splat2(eb.w), rW[7], ex);
    f32x2 s = up2p(h) + ex;
    s = __builtin_elementwise_max(s, splat2(0.f));
    acc += s;
}

// flattened group stream per wave (144B inline-attr groups); node boundaries
// are wave-uniform scalar events. Block 0 also zeroes the stats buffer.
__global__ __launch_bounds__(256) void aggr_kernel(
    const int* __restrict__ grpptr, const char* __restrict__ rec,
    const float* __restrict__ Wel, const float* __restrict__ bel,
    const u16* __restrict__ hin, u16* __restrict__ z,
    const int* __restrict__ wstart, float* __restrict__ stats)
{
    const int lane = threadIdx.x & 63;
    const int cb = lane * 4;
    const int wid = __builtin_amdgcn_readfirstlane((blockIdx.x << 2) + (threadIdx.x >> 6));

    if (blockIdx.x == 0) {
        #pragma unroll
        for (int i = 0; i < 8; ++i) stats[i * 256 + threadIdx.x] = 0.f;
    }

    f32x2 rW[EFEAT];
    #pragma unroll
    for (int k = 0; k < EFEAT; ++k) {
        float2 t = *(const float2*)(Wel + k * DIM + lane * 2);
        rW[k].x = t.x; rW[k].y = t.y;
    }
    float2 tb = *(const float2*)(bel + lane * 2);
    f32x2 rB; rB.x = tb.x; rB.y = tb.y;

    const char* hinB = (const char*)hin;
    int n = wstart[wid];
    const int n1 = wstart[wid + 1];

    // leading empty nodes: z = h_in row
    while (n < n1 && grpptr[n + 1] == grpptr[n]) {
        f32x2 a0 = up2p(*(const u32*)(hinB + ((u32)n << 8) + cb));
        *(u32*)(z + ((size_t)n << 7) + lane * 2) = pk2(a0.x, a0.y);
        ++n;
    }
    if (n < n1) {
        int g = grpptr[n];
        const int gTot = grpptr[n1];
        int gEnd = grpptr[n + 1];
        f32x2 acc = up2p(*(const u32*)(hinB + ((u32)n << 8) + cb));
        const char* rb = rec + (size_t)g * 144;

        uint4 so = *(const uint4*)rb;
        u32 h0 = *(const u32*)(hinB + so.x + cb);
        u32 h1 = *(const u32*)(hinB + so.y + cb);
        u32 h2 = *(const u32*)(hinB + so.z + cb);
        u32 h3 = *(const u32*)(hinB + so.w + cb);
        f32x4v e0a = *(const f32x4v*)(rb + 16);
        f32x4v e0b = *(const f32x4v*)(rb + 32);
        f32x4v e1a = *(const f32x4v*)(rb + 48);
        f32x4v e1b = *(const f32x4v*)(rb + 64);
        f32x4v e2a = *(const f32x4v*)(rb + 80);
        f32x4v e2b = *(const f32x4v*)(rb + 96);
        f32x4v e3a = *(const f32x4v*)(rb + 112);
        f32x4v e3b = *(const f32x4v*)(rb + 128);
        uint4 soN = *(const uint4*)(rb + 144);

        #pragma unroll 2
        for (; g < gTot; ++g, rb += 144) {
            u32 i0 = *(const u32*)(hinB + soN.x + cb);
            u32 i1 = *(const u32*)(hinB + soN.y + cb);
            u32 i2 = *(const u32*)(hinB + soN.z + cb);
            u32 i3 = *(const u32*)(hinB + soN.w + cb);
            f32x4v f0a = *(const f32x4v*)(rb + 160);
            f32x4v f0b = *(const f32x4v*)(rb + 176);
            f32x4v f1a = *(const f32x4v*)(rb + 192);
            f32x4v f1b = *(const f32x4v*)(rb + 208);
            f32x4v f2a = *(const f32x4v*)(rb + 224);
            f32x4v f2b = *(const f32x4v*)(rb + 240);
            f32x4v f3a = *(const f32x4v*)(rb + 256);
            f32x4v f3b = *(const f32x4v*)(rb + 272);
            uint4 soNN = *(const uint4*)(rb + 288);
            edge_term_f(h0, e0a, e0b, rW, rB, acc);
            edge_term_f(h1, e1a, e1b, rW, rB, acc);
            edge_term_f(h2, e2a, e2b, rW, rB, acc);
            edge_term_f(h3, e3a, e3b, rW, rB, acc);
            h0 = i0; h1 = i1; h2 = i2; h3 = i3;
            e0a = f0a; e0b = f0b; e1a = f1a; e1b = f1b;
            e2a = f2a; e2b = f2b; e3a = f3a; e3b = f3b;
            soN = soNN;
            if (g + 1 == gEnd) {
                *(u32*)(z + ((size_t)n << 7) + lane * 2) = pk2(acc.x, acc.y);
                ++n;
                if (g + 1 < gTot) {
                    while (grpptr[n + 1] == grpptr[n]) {
                        f32x2 a0 = up2p(*(const u32*)(hinB + ((u32)n << 8) + cb));
                        *(u32*)(z + ((size_t)n << 7) + lane * 2) = pk2(a0.x, a0.y);
                        ++n;
                    }
                    acc = up2p(*(const u32*)(hinB + ((u32)n << 8) + cb));
                    gEnd = grpptr[n + 1];
                }
            }
        }
    }
    while (n < n1) {
        f32x2 a0 = up2p(*(const u32*)(hinB + ((u32)n << 8) + cb));
        *(u32*)(z + ((size_t)n << 7) + lane * 2) = pk2(a0.x, a0.y);
        ++n;
    }
}

// ---------------------------------------------------------------- bf16 MFMA GEMM, BMx128 tile (two B-halves), BK=128
// BM=128: 2x2 wave grid (rows 2x64). BM=64: rows 2x32 -> twice the blocks for small-N shapes.
template <int MODE, bool CBF16, int BM>
__global__ __launch_bounds__(256) void gemm_bf16_kernel(
    const u16* __restrict__ Aa,
    const float* __restrict__ sSum, const float* __restrict__ sSS,
    const float* __restrict__ gA, const float* __restrict__ btA, float invCnt,
    const u16* __restrict__ Bt,          // [Nc][K] bf16
    const float* __restrict__ bias,
    void* __restrict__ CoutV,
    float* __restrict__ outSum, float* __restrict__ outSS,
    int M, int K, int Nc)
{
    constexpr int BN = 128, BK = 128;
    constexpr int LDA = BK + 8;
    constexpr int MR = BM / 32;          // acc row-fragments per wave
    __shared__ u16 As[BM * LDA];
    __shared__ u16 Bs[64 * LDA];
    __shared__ float csum[BN], css[BN];

    const int tid = threadIdx.x;
    const int wave = tid >> 6, lane = tid & 63;
    const int row0 = blockIdx.x * BM, col0 = blockIdx.y * BN;
    const int w_m = (wave & 1) * (BM / 2), w_n = (wave >> 1) * 32;
    const int quad = lane >> 4, l16 = lane & 15;

    if (tid < BN) { csum[tid] = 0.f; css[tid] = 0.f; }

    f32x4_t acc[MR][4];
    #pragma unroll
    for (int mi = 0; mi < MR; ++mi)
        #pragma unroll
        for (int ni = 0; ni < 4; ++ni)
            acc[mi][ni] = (f32x4_t){0.f, 0.f, 0.f, 0.f};

    const int kc = (tid & 15) * 8;
    const int nkt = K / BK;

    for (int kt = 0; kt < nkt; ++kt) {
        float af[8], bf_[8];
        if (MODE == 1) {
            #pragma unroll
            for (int j = 0; j < 8; ++j) {
                int kg = kt * BK + kc + j;
                float m = sSum[kg] * invCnt;
                float var = sSS[kg] * invCnt - m * m;
                float r = rsqrtf(var + BN_EPS);
                float a = gA[kg] * r;
                af[j] = a;
                bf_[j] = btA[kg] - m * a;
            }
        }
        #pragma unroll
        for (int it = 0; it < BM / 16; ++it) {
            int chunk = it * 256 + tid;
            int row = chunk >> 4;
            int gr = row0 + row; if (gr >= M) gr = M - 1;
            uint4 q = *(const uint4*)(Aa + (size_t)gr * K + kt * BK + kc);
            if (MODE == 1) {
                float2 p0 = up2(q.x), p1 = up2(q.y), p2 = up2(q.z), p3 = up2(q.w);
                p0.x = fmaxf(fmaf(af[0], p0.x, bf_[0]), 0.f);
                p0.y = fmaxf(fmaf(af[1], p0.y, bf_[1]), 0.f);
                p1.x = fmaxf(fmaf(af[2], p1.x, bf_[2]), 0.f);
                p1.y = fmaxf(fmaf(af[3], p1.y, bf_[3]), 0.f);
                p2.x = fmaxf(fmaf(af[4], p2.x, bf_[4]), 0.f);
                p2.y = fmaxf(fmaf(af[5], p2.y, bf_[5]), 0.f);
                p3.x = fmaxf(fmaf(af[6], p3.x, bf_[6]), 0.f);
                p3.y = fmaxf(fmaf(af[7], p3.y, bf_[7]), 0.f);
                q.x = pk2(p0.x, p0.y); q.y = pk2(p1.x, p1.y);
                q.z = pk2(p2.x, p2.y); q.w = pk2(p3.x, p3.y);
            }
            *(uint4*)(As + row * LDA + kc) = q;
        }
        #pragma unroll
        for (int half = 0; half < 2; ++half) {
            #pragma unroll
            for (int it = 0; it < 4; ++it) {
                int chunk = it * 256 + tid;
                int n = chunk >> 4;
                uint4 q = *(const uint4*)(Bt + (size_t)(col0 + half * 64 + n) * K + kt * BK + kc);
                *(uint4*)(Bs + n * LDA + kc) = q;
            }
            __syncthreads();
            #pragma unroll
            for (int ks = 0; ks < 4; ++ks) {
                bf16x8_t a_frag[MR], b_frag[2];
                #pragma unroll
                for (int mi = 0; mi < MR; ++mi)
                    a_frag[mi] = *(const bf16x8_t*)(As + (w_m + mi * 16 + l16) * LDA + ks * 32 + quad * 8);
                #pragma unroll
                for (int ni = 0; ni < 2; ++ni)
                    b_frag[ni] = *(const bf16x8_t*)(Bs + (w_n + ni * 16 + l16) * LDA + ks * 32 + quad * 8);
                #pragma unroll
                for (int mi = 0; mi < MR; ++mi)
                    #pragma unroll
                    for (int ni = 0; ni < 2; ++ni)
                        acc[mi][half * 2 + ni] = __builtin_amdgcn_mfma_f32_16x16x32_bf16(
                            a_frag[mi], b_frag[ni], acc[mi][half * 2 + ni], 0, 0, 0);
            }
            __syncthreads();
        }
    }

    u16* Cb = (u16*)CoutV;
    float* Cf = (float*)CoutV;
    #pragma unroll
    for (int half = 0; half < 2; ++half)
    #pragma unroll
    for (int ni = 0; ni < 2; ++ni) {
        int ccol = half * 64 + w_n + ni * 16 + l16;
        int col = col0 + ccol;
        float bv = bias[col];
        float s = 0.f, qs = 0.f;
        #pragma unroll
        for (int mi = 0; mi < MR; ++mi) {
            int rbase = row0 + w_m + mi * 16 + quad * 4;
            #pragma unroll
            for (int reg = 0; reg < 4; ++reg) {
                int gr = rbase + reg;
                if (gr < M) {
                    float o = acc[mi][half * 2 + ni][reg] + bv;
                    s += o;
                    qs += o * o;
                    if (CBF16) Cb[(size_t)gr * Nc + col] = f2bf(o);
                    else       Cf[(size_t)gr * Nc + col] = o;
                }
            }
        }
        s += __shfl_xor(s, 16);  s += __shfl_xor(s, 32);
        qs += __shfl_xor(qs, 16);  qs += __shfl_xor(qs, 32);
        if (quad == 0) {
            atomicAdd(&csum[ccol], s);
            atomicAdd(&css[ccol], qs);
        }
    }
    __syncthreads();
    if (tid < BN) {
        atomic_add_f(outSum + col0 + tid, csum[tid]);
        atomic_add_f(outSS + col0 + tid, css[tid]);
    }
}

// ---------------------------------------------------------------- fp32 GEMM (VN path, tiny M)
template <int MODE>
__global__ __launch_bounds__(256) void gemm_kernel(
    const float* __restrict__ Aa,
    const float* __restrict__ sSum, const float* __restrict__ sSS,
    const float* __restrict__ gA, const float* __restrict__ btA, float invCnt,
    const float* __restrict__ B, const float* __restrict__ bias,
    float* __restrict__ Cout, float* __restrict__ outSum, float* __restrict__ outSS,
    int M, int K, int Nc)
{
    __shared__ float As[16][68];
    __shared__ float Bs[16][64];
    __shared__ float alphaS[256], betaS[256];
    __shared__ float csum[64], css[64];

    const int tid = threadIdx.x;
    const int tx = tid & 15, ty = tid >> 4;
    const int row0 = blockIdx.x * 64, col0 = blockIdx.y * 64;

    if (tid < 64) { csum[tid] = 0.f; css[tid] = 0.f; }
    if (MODE == 1) {
        for (int k = tid; k < K; k += 256) {
            float m = sSum[k] * invCnt;
            float var = sSS[k] * invCnt - m * m;
            float r = rsqrtf(var + BN_EPS);
            float a = gA[k] * r;
            alphaS[k] = a;
            betaS[k] = btA[k] - m * a;
        }
    }
    __syncthreads();

    float acc[4][4];
    #pragma unroll
    for (int i = 0; i < 4; ++i)
        #pragma unroll
        for (int j = 0; j < 4; ++j) acc[i][j] = 0.f;

    const int lr = tid >> 2;
    const int lk = (tid & 3) * 4;
    const int bk = tid >> 4;
    const int bc = tx * 4;

    for (int kt = 0; kt < K; kt += 16) {
        int gr = row0 + lr;
        float4 va = make_float4(0.f, 0.f, 0.f, 0.f);
        if (gr < M) {
            va = *(const float4*)(Aa + (size_t)gr * K + kt + lk);
            if (MODE == 1) {
                int k0 = kt + lk;
                va.x = fmaxf(fmaf(alphaS[k0 + 0], va.x, betaS[k0 + 0]), 0.f);
                va.y = fmaxf(fmaf(alphaS[k0 + 1], va.y, betaS[k0 + 1]), 0.f);
                va.z = fmaxf(fmaf(alphaS[k0 + 2], va.z, betaS[k0 + 2]), 0.f);
                va.w = fmaxf(fmaf(alphaS[k0 + 3], va.w, betaS[k0 + 3]), 0.f);
            }
        }
        As[lk + 0][lr] = va.x;
        As[lk + 1][lr] = va.y;
        As[lk + 2][lr] = va.z;
        As[lk + 3][lr] = va.w;
        const float4 vb4 = *(const float4*)(B + (size_t)(kt + bk) * Nc + col0 + bc);
        *(float4*)&Bs[bk][bc] = vb4;
        __syncthreads();
        #pragma unroll
        for (int kk = 0; kk < 16; ++kk) {
            const float4 a4 = *(const float4*)&As[kk][ty * 4];
            const float4 b4 = *(const float4*)&Bs[kk][tx * 4];
            float av[4] = {a4.x, a4.y, a4.z, a4.w};
            float bv4[4] = {b4.x, b4.y, b4.z, b4.w};
            #pragma unroll
            for (int i = 0; i < 4; ++i)
                #pragma unroll
                for (int j = 0; j < 4; ++j)
                    acc[i][j] = fmaf(av[i], bv4[j], acc[i][j]);
        }
        __syncthreads();
    }

    const float4 bvv = *(const float4*)(bias + col0 + tx * 4);
    float bias4[4] = {bvv.x, bvv.y, bvv.z, bvv.w};
    float ps[4] = {0.f, 0.f, 0.f, 0.f};
    float pq[4] = {0.f, 0.f, 0.f, 0.f};
    #pragma unroll
    for (int i = 0; i < 4; ++i) {
        int gr = row0 + ty * 4 + i;
        if (gr < M) {
            float o[4];
            #pragma unroll
            for (int j = 0; j < 4; ++j) {
                o[j] = acc[i][j] + bias4[j];
                ps[j] += o[j];
                pq[j] += o[j] * o[j];
            }
            *(float4*)(Cout + (size_t)gr * Nc + col0 + tx * 4) = make_float4(o[0], o[1], o[2], o[3]);
        }
    }
    #pragma unroll
    for (int j = 0; j < 4; ++j) {
        atomicAdd(&csum[tx * 4 + j], ps[j]);
        atomicAdd(&css[tx * 4 + j], pq[j]);
    }
    __syncthreads();
    if (tid < 64) {
        atomic_add_f(outSum + col0 + tid, csum[tid]);
        atomic_add_f(outSS + col0 + tid, css[tid]);
    }
}

// ---------------------------------------------------------------- pooled[g] = vn[g] + segment_sum(h_in, batch)[g]
template <int VNM>
__global__ __launch_bounds__(64) void pooled_seg_kernel(
    const u16* __restrict__ hin, const int* __restrict__ batch,
    const float* __restrict__ vn_emb,
    const float* __restrict__ vnpre, const float* __restrict__ vsum, const float* __restrict__ vss,
    const float* __restrict__ gv, const float* __restrict__ btv, float invG,
    float* __restrict__ pooled)
{
    int g = blockIdx.x;
    int lane = threadIdx.x;
    int c2 = lane * 2;
    int lo = 0, hi = N_NODES;
    while (lo < hi) { int mid = (lo + hi) >> 1; if (batch[mid] < g) lo = mid + 1; else hi = mid; }
    int start = lo;
    hi = N_NODES;
    while (lo < hi) { int mid = (lo + hi) >> 1; if (batch[mid] < g + 1) lo = mid + 1; else hi = mid; }
    int end = lo;

    f32x2 acc;
    if (VNM == 0) {
        float2 w = *(const float2*)(vn_emb + c2);
        acc.x = w.x; acc.y = w.y;
    } else {
        float2 vs = *(const float2*)(vsum + c2);
        float2 vq = *(const float2*)(vss + c2);
        float2 gg = *(const float2*)(gv + c2);
        float2 bt = *(const float2*)(btv + c2);
        float2 vp = *(const float2*)(vnpre + (size_t)g * DIM + c2);
        float m0 = vs.x * invG, m1 = vs.y * invG;
        float va0 = vq.x * invG - m0 * m0, va1 = vq.y * invG - m1 * m1;
        float a0 = gg.x * rsqrtf(va0 + BN_EPS), a1 = gg.y * rsqrtf(va1 + BN_EPS);
        acc.x = fmaxf(fmaf(a0, vp.x, bt.x - m0 * a0), 0.f);
        acc.y = fmaxf(fmaf(a1, vp.y, bt.y - m1 * a1), 0.f);
    }

    const char* hinB = (const char*)hin;
    const int cb = lane * 4;
    f32x2 s0 = splat2(0.f), s1 = splat2(0.f), s2 = splat2(0.f), s3 = splat2(0.f);
    int n = start;
    for (; n + 3 < end; n += 4) {
        s0 += up2p(*(const u32*)(hinB + ((size_t)(n + 0) << 8) + cb));
        s1 += up2p(*(const u32*)(hinB + ((size_t)(n + 1) << 8) + cb));
        s2 += up2p(*(const u32*)(hinB + ((size_t)(n + 2) << 8) + cb));
        s3 += up2p(*(const u32*)(hinB + ((size_t)(n + 3) << 8) + cb));
    }
    for (; n < end; ++n) s0 += up2p(*(const u32*)(hinB + ((size_t)n << 8) + cb));
    acc += (s0 + s1) + (s2 + s3);
    *(float2*)(pooled + (size_t)g * DIM + c2) = make_float2(acc.x, acc.y);
}

// ---------------------------------------------------------------- final in-place BN on d_out (no relu)
__global__ __launch_bounds__(256) void final_bn_kernel(
    float* __restrict__ outp, const float* __restrict__ sum2, const float* __restrict__ ss2,
    const float* __restrict__ g, const float* __restrict__ b, float invN, int total4)
{
    int idx = blockIdx.x * 256 + threadIdx.x;
    if (idx >= total4) return;
    int base = idx * 4;
    int c = base & (DIM - 1);
    float4 v = *(const float4*)(outp + base);
    float o[4] = {v.x, v.y, v.z, v.w};
    #pragma unroll
    for (int j = 0; j < 4; ++j) {
        int cj = c + j;
        float m = sum2[cj] * invN;
        float var = ss2[cj] * invN - m * m;
        float r = rsqrtf(var + BN_EPS);
        float a = g[cj] * r;
        o[j] = fmaf(a, o[j], b[cj] - m * a);
    }
    *(float4*)(outp + base) = make_float4(o[0], o[1], o[2], o[3]);
}

// ---------------------------------------------------------------- launch
extern "C" void kernel_launch(void* const* d_in, const int* in_sizes, int n_in,
                              void* d_out, int out_size, void* d_ws, size_t ws_size,
                              hipStream_t stream) {
    const float* x         = (const float*)d_in[0];
    const float* edge_attr = (const float*)d_in[1];
    const float* vn_emb    = (const float*)d_in[2];
    const float* We        = (const float*)d_in[3];
    const float* be        = (const float*)d_in[4];
    const float* W1        = (const float*)d_in[5];
    const float* b1        = (const float*)d_in[6];
    const float* g1v       = (const float*)d_in[7];
    const float* bt1       = (const float*)d_in[8];
    const float* W2        = (const float*)d_in[9];
    const float* b2        = (const float*)d_in[10];
    const float* gb        = (const float*)d_in[11];
    const float* bb        = (const float*)d_in[12];
    const float* Wv1       = (const float*)d_in[13];
    const float* bv1       = (const float*)d_in[14];
    const float* gv1       = (const float*)d_in[15];
    const float* btv1      = (const float*)d_in[16];
    const float* Wv2       = (const float*)d_in[17];
    const float* bv2       = (const float*)d_in[18];
    const float* gv2       = (const float*)d_in[19];
    const float* btv2      = (const float*)d_in[20];
    const int* edge_index  = (const int*)d_in[21];
    const int* batch       = (const int*)d_in[22];
    float* outp = (float*)d_out;

    auto au = [](size_t x) { return (x + 255) & ~(size_t)255; };
    char* p = (char*)d_ws;
    u16* h_in   = (u16*)p;  p += au((size_t)(N_NODES + 1) * DIM * 2);   // +1 sentinel row
    u16* z_bf   = (u16*)p;  p += au((size_t)N_NODES * DIM * 2);
    u16* c1_bf  = (u16*)p;  p += au((size_t)N_NODES * HID * 2);
    u16* W1t    = (u16*)p;  p += au((size_t)3 * 32768 * 2);
    u16* W2t    = (u16*)p;  p += au((size_t)3 * 32768 * 2);
    float* pooled = (float*)p;  p += au((size_t)N_GRAPH * DIM * 4);
    float* tpre   = (float*)p;  p += au((size_t)N_GRAPH * HID * 4);
    float* vnpre  = (float*)p;  p += au((size_t)N_GRAPH * DIM * 4);
    float* stats  = (float*)p;  p += au(2048 * 4);
    float* sum1 = stats,        *ss1 = stats + 256;
    float* sum2 = stats + 512,  *ss2 = stats + 640;
    float* vsum1 = stats + 768, *vss1 = stats + 1024;
    float* vsum2 = stats + 1280, *vss2 = stats + 1408;
    int* grpptr = (int*)p;  p += au((size_t)(N_NODES + 1) * 4);
    int* wstart = (int*)p;  p += au((size_t)(AGGR_WAVES + 1) * 4);
    int* bsum   = (int*)p;  p += au((size_t)SCAN_BLOCKS * 4);
    char* brec  = p;        p += au((size_t)(MAX_GROUPS + 4) * 144 + 512);
    // prep-only aliases over layer-phase buffers:
    int* deg   = (int*)z_bf;                       // hist/scan only, before aggr writes z
    int* rank  = (int*)c1_bf;                      // scatter only (3.2MB)
    uint2* srec = (uint2*)(c1_bf + au((size_t)N_EDGES * 4) / 2);  // compact rec inside c1

    const float invN = 1.0f / (float)N_NODES;
    const float invG = 1.0f / (float)N_GRAPH;
    const int total4 = N_NODES * DIM / 4;
    const int nslots = (MAX_GROUPS + 4) * 4;

    // ---- one-time prep ----
    hipMemsetAsync(deg, 0, N_NODES * sizeof(int), stream);
    hist_rank_kernel<<<(N_EDGES + 255) / 256, 256, 0, stream>>>(edge_index, deg, rank);
    scan1_kernel<<<SCAN_BLOCKS, 1024, 0, stream>>>(deg, grpptr, bsum);
    scan2_kernel<<<1, 64, 0, stream>>>(bsum);
    scan3_kernel<<<SCAN_BLOCKS, 1024, 0, stream>>>(grpptr, bsum);
    padinit_kernel<<<(nslots / 2 + 255) / 256, 256, 0, stream>>>((uint4*)srec, nslots / 2, h_in);
    scatter_kernel<<<(N_EDGES + 255) / 256, 256, 0, stream>>>(
        edge_index, rank, grpptr, srec);
    expand_kernel<<<(nslots + 255) / 256, 256, 0, stream>>>(
        srec, edge_attr, brec, nslots);
    wstart_kernel<<<(AGGR_WAVES + 256) / 256, 256, 0, stream>>>(grpptr, wstart);
    wconv_kernel<<<768, 256, 0, stream>>>(W1, W2, W1t, W2t);

    const int AGGR_BLOCKS = AGGR_WAVES / 4;

    for (int l = 0; l < N_LAYER; ++l) {
        if (l == 0)
            hin_kernel<false, 0><<<(total4 + 255) / 256, 256, 0, stream>>>(
                x, nullptr, nullptr, nullptr, nullptr, 0.f, batch,
                vn_emb, nullptr, nullptr, nullptr, nullptr, nullptr, 0.f,
                h_in, total4);
        else
            hin_kernel<true, 1><<<(total4 + 255) / 256, 256, 0, stream>>>(
                outp, sum2, ss2, gb + (size_t)(l - 1) * DIM, bb + (size_t)(l - 1) * DIM, invN, batch,
                nullptr, vnpre, vsum2, vss2,
                gv2 + (size_t)(l - 1) * DIM, btv2 + (size_t)(l - 1) * DIM, invG,
                h_in, total4);

        if (l == 0)
            pooled_seg_kernel<0><<<N_GRAPH, 64, 0, stream>>>(
                h_in, batch, vn_emb, nullptr, nullptr, nullptr, nullptr, nullptr, 0.f, pooled);
        else if (l < N_LAYER - 1)
            pooled_seg_kernel<1><<<N_GRAPH, 64, 0, stream>>>(
                h_in, batch, nullptr, vnpre, vsum2, vss2,
                gv2 + (size_t)(l - 1) * DIM, btv2 + (size_t)(l - 1) * DIM, invG, pooled);

        aggr_kernel<<<AGGR_BLOCKS, 256, 0, stream>>>(
            grpptr, brec, We + (size_t)l * EFEAT * DIM, be + (size_t)l * DIM,
            h_in, z_bf, wstart, stats);

        // c1 = z @ W1: M=50000, K=128, N=256 -> BM=128, grid (391, 2)
        dim3 g1d((N_NODES + 127) / 128, HID / 128);
        gemm_bf16_kernel<0, true, 128><<<g1d, 256, 0, stream>>>(
            z_bf, nullptr, nullptr, nullptr, nullptr, 0.f,
            W1t + (size_t)l * 32768, b1 + (size_t)l * HID,
            (void*)c1_bf, sum1, ss1, N_NODES, DIM, HID);

        // h = bn(c1)relu @ W2: M=50000, K=256, N=128 -> BM=64, grid (782, 1)
        dim3 g2d((N_NODES + 63) / 64, DIM / 128);
        gemm_bf16_kernel<1, false, 64><<<g2d, 256, 0, stream>>>(
            c1_bf, sum1, ss1, g1v + (size_t)l * HID, bt1 + (size_t)l * HID, invN,
            W2t + (size_t)l * 32768, b2 + (size_t)l * DIM,
            (void*)outp, sum2, ss2, N_NODES, HID, DIM);

        if (l < N_LAYER - 1) {
            dim3 g3d(N_GRAPH / 64, HID / 64);
            gemm_kernel<0><<<g3d, 256, 0, stream>>>(
                pooled, nullptr, nullptr, nullptr, nullptr, 0.f,
                Wv1 + (size_t)l * DIM * HID, bv1 + (size_t)l * HID,
                tpre, vsum1, vss1, N_GRAPH, DIM, HID);

            dim3 g4d(N_GRAPH / 64, DIM / 64);
            gemm_kernel<1><<<g4d, 256, 0, stream>>>(
                tpre, vsum1, vss1, gv1 + (size_t)l * HID, btv1 + (size_t)l * HID, invG,
                Wv2 + (size_t)l * HID * DIM, bv2 + (size_t)l * DIM,
                vnpre, vsum2, vss2, N_GRAPH, HID, DIM);
        }
    }

    final_bn_kernel<<<(total4 + 255) / 256, 256, 0, stream>>>(
        outp, sum2, ss2, gb + (size_t)2 * DIM, bb + (size_t)2 * DIM, invN, total4);
}

// Round 9
// 707.073 us; speedup vs baseline: 1.0978x; 1.0978x over previous
//
#include <hip/hip_runtime.h>
#include <hip/hip_bf16.h>

#define N_NODES 50000
#define N_EDGES 800000
#define DIM 128
#define HID 256
#define N_GRAPH 512
#define N_LAYER 3
#define EFEAT 8
#define BN_EPS 1e-5f
#define MAX_GROUPS 240000   // >= sum(ceil(deg/4)) <= (E + 3N)/4 = 237500
#define AGGR_WAVES 8192
#define SCAN_BLOCKS ((N_NODES + 1023) / 1024)

typedef unsigned short u16;
typedef unsigned int u32;

using bf16x8_t = short __attribute__((ext_vector_type(8)));
using f32x4_t  = float __attribute__((ext_vector_type(4)));
using f32x2    = float __attribute__((ext_vector_type(2)));
using f32x4v   = float __attribute__((ext_vector_type(4)));

// ---------------------------------------------------------------- utilities

__device__ __forceinline__ void atomic_add_f(float* p, float v) {
    unsafeAtomicAdd(p, v);
}
__device__ __forceinline__ u16 f2bf(float x) {
    union { float f; u32 u; } v; v.f = x;
    u32 r = v.u + 0x7FFF + ((v.u >> 16) & 1);
    return (u16)(r >> 16);
}
__device__ __forceinline__ float bf2f(u16 u) {
    union { u32 i; float f; } v; v.i = (u32)u << 16; return v.f;
}
__device__ __forceinline__ float2 up2(u32 p) {
    return make_float2(bf2f((u16)(p & 0xFFFF)), bf2f((u16)(p >> 16)));
}
__device__ __forceinline__ u32 pk2(float a, float b) {
    return (u32)f2bf(a) | ((u32)f2bf(b) << 16);
}
__device__ __forceinline__ f32x2 up2p(u32 p) {
    union { u32 u[2]; f32x2 f; } v;
    v.u[0] = p << 16;
    v.u[1] = p & 0xFFFF0000u;
    return v.f;
}
__device__ __forceinline__ f32x2 splat2(float x) {
    f32x2 r; r.x = x; r.y = x; return r;
}

// ---------------------------------------------------------------- weight transpose+convert to bf16
__global__ __launch_bounds__(256) void wconv_kernel(
    const float* __restrict__ W1, const float* __restrict__ W2,
    u16* __restrict__ W1t, u16* __restrict__ W2t)
{
    int idx = blockIdx.x * 256 + threadIdx.x;
    if (idx >= 6 * 32768) return;
    int m = idx >> 15;
    int off = idx & 32767;
    int l = m >> 1;
    if ((m & 1) == 0) {
        int r = off >> 8, c = off & 255;
        W1t[(size_t)l * 32768 + c * 128 + r] = f2bf(W1[(size_t)l * 32768 + r * 256 + c]);
    } else {
        int r = off >> 7, c = off & 127;
        W2t[(size_t)l * 32768 + c * 256 + r] = f2bf(W2[(size_t)l * 32768 + r * 128 + c]);
    }
}

// ---------------------------------------------------------------- CSR build
__global__ __launch_bounds__(256) void hist_rank_kernel(
    const int* __restrict__ ei, int* __restrict__ deg, int* __restrict__ rank)
{
    int e = blockIdx.x * 256 + threadIdx.x;
    if (e >= N_EDGES) return;
    int dst = ei[N_EDGES + e];
    rank[e] = atomicAdd(&deg[dst], 1);
}

// ---- multi-block scan over ceil(deg/4) (3 phases, all parallel) ----
__global__ __launch_bounds__(1024) void scan1_kernel(
    const int* __restrict__ deg, int* __restrict__ grpptr, int* __restrict__ bsum)
{
    __shared__ int wsum[16];
    int blk = blockIdx.x, tid = threadIdx.x;
    int i = blk * 1024 + tid;
    int v = (i < N_NODES) ? ((deg[i] + 3) >> 2) : 0;
    int lane = tid & 63, w = tid >> 6;
    int s = v;
    #pragma unroll
    for (int d = 1; d < 64; d <<= 1) { int t = __shfl_up(s, d); if (lane >= d) s += t; }
    if (lane == 63) wsum[w] = s;
    __syncthreads();
    if (tid < 64) {
        int t = (tid < 16) ? wsum[tid] : 0;
        #pragma unroll
        for (int d = 1; d < 16; d <<= 1) { int u = __shfl_up(t, d); if (tid >= d) t += u; }
        if (tid < 16) wsum[tid] = t;
    }
    __syncthreads();
    int excl = (w > 0) ? wsum[w - 1] : 0;
    int incl = s + excl;
    if (i < N_NODES) grpptr[i + 1] = incl;
    if (tid == 1023) bsum[blk] = incl;
}

__global__ __launch_bounds__(64) void scan2_kernel(int* __restrict__ bsum) {
    int tid = threadIdx.x;
    int v = (tid < SCAN_BLOCKS) ? bsum[tid] : 0;
    int s = v;
    #pragma unroll
    for (int d = 1; d < 64; d <<= 1) { int t = __shfl_up(s, d); if (tid >= d) s += t; }
    if (tid < SCAN_BLOCKS) bsum[tid] = s - v;   // exclusive
}

__global__ __launch_bounds__(1024) void scan3_kernel(
    int* __restrict__ grpptr, const int* __restrict__ bsum)
{
    int blk = blockIdx.x;
    int i = blk * 1024 + threadIdx.x;
    if (i < N_NODES) grpptr[i + 1] += bsum[blk];
    if (blk == 0 && threadIdx.x == 0) grpptr[0] = 0;
}

// init every 8B slot of the compact rec: {so=sentinel row, eaOff=0} x2 per uint4.
// Also fills the sentinel h_in row (bf16 -3.39e38) from block 0.
__global__ __launch_bounds__(256) void padinit_kernel(
    uint4* __restrict__ rec4, int nq, u16* __restrict__ hin)
{
    int i = blockIdx.x * 256 + threadIdx.x;
    if (blockIdx.x == 0 && threadIdx.x < 64)
        *(u32*)(hin + (size_t)N_NODES * DIM + threadIdx.x * 2) = 0xFF7FFF7Fu;
    if (i >= nq) return;
    u32 s = (u32)N_NODES << 8;
    rec4[i] = make_uint4(s, 0u, s, 0u);
}

// Pass 2 (NO atomics): one uint2 store per edge: {src row byte off, ea byte off}.
__global__ __launch_bounds__(256) void scatter_kernel(
    const int* __restrict__ ei,
    const int* __restrict__ rank, const int* __restrict__ grpptr,
    uint2* __restrict__ srec)
{
    int e = blockIdx.x * 256 + threadIdx.x;
    if (e >= N_EDGES) return;
    int src = __builtin_nontemporal_load(ei + e);
    int dst = __builtin_nontemporal_load(ei + N_EDGES + e);
    int rk  = __builtin_nontemporal_load(rank + e);
    int slot = (grpptr[dst] + (rk >> 2)) * 4 + (rk & 3);
    uint2 v;
    v.x = (u32)src << 8;        // hin row byte offset (DIM*2 = 256B rows)
    v.y = (u32)e << 5;          // edge_attr byte offset (EFEAT*4 = 32B rows)
    srec[slot] = v;
}

// Pass 3: expand compact records into 144B inline-attr groups.
__global__ __launch_bounds__(256) void expand_kernel(
    const uint2* __restrict__ srec, const float* __restrict__ ea,
    char* __restrict__ brec, int nslots)
{
    int i = blockIdx.x * 256 + threadIdx.x;
    if (i >= nslots) return;
    int g = i >> 2;
    int j = i & 3;
    uint2 v = srec[i];
    const char* eaB = (const char*)ea;
    f32x4v lo = *(const f32x4v*)(eaB + v.y);
    f32x4v hi = *(const f32x4v*)(eaB + v.y + 16);
    char* rb = brec + (size_t)g * 144;
    *(u32*)(rb + j * 4) = v.x;
    *(f32x4v*)(rb + 16 + j * 32) = lo;
    *(f32x4v*)(rb + 32 + j * 32) = hi;
}

// per-wave start node: balance by group count (binary search on grpptr)
__global__ __launch_bounds__(256) void wstart_kernel(
    const int* __restrict__ grpptr, int* __restrict__ wstart)
{
    int w = blockIdx.x * 256 + threadIdx.x;
    if (w > AGGR_WAVES) return;
    if (w == AGGR_WAVES) { wstart[w] = N_NODES; return; }
    int Gt = grpptr[N_NODES];
    int q = (int)(((long long)w * Gt) / AGGR_WAVES);
    int lo = 0, hi = N_NODES;
    while (lo < hi) { int mid = (lo + hi) >> 1; if (grpptr[mid] < q) lo = mid + 1; else hi = mid; }
    wstart[w] = lo;
}

// ---------------------------------------------------------------- h_in = act(src) + vn[batch]  (bf16 out)
template <bool USEBN, int VNM>
__global__ __launch_bounds__(256) void hin_kernel(
    const float* __restrict__ src,
    const float* __restrict__ sum2, const float* __restrict__ ss2,
    const float* __restrict__ g, const float* __restrict__ b, float invN,
    const int* __restrict__ batch,
    const float* __restrict__ vn_emb,
    const float* __restrict__ vnpre, const float* __restrict__ vsum, const float* __restrict__ vss,
    const float* __restrict__ gv, const float* __restrict__ btv, float invG,
    u16* __restrict__ hin, int total4)
{
    int idx = blockIdx.x * 256 + threadIdx.x;
    if (idx >= total4) return;
    int base = idx * 4;
    int n = base >> 7;
    int c = base & (DIM - 1);
    float4 v = *(const float4*)(src + base);
    float o[4] = {v.x, v.y, v.z, v.w};
    if (USEBN) {
        #pragma unroll
        for (int j = 0; j < 4; ++j) {
            int cj = c + j;
            float m = sum2[cj] * invN;
            float var = ss2[cj] * invN - m * m;
            float r = rsqrtf(var + BN_EPS);
            float a = g[cj] * r;
            o[j] = fmaxf(fmaf(a, o[j], b[cj] - m * a), 0.f);
        }
    }
    int grp = batch[n];
    if (VNM == 0) {
        const float4 w = *(const float4*)(vn_emb + c);
        o[0] += w.x; o[1] += w.y; o[2] += w.z; o[3] += w.w;
    } else {
        const float4 vp = *(const float4*)(vnpre + (size_t)grp * DIM + c);
        float vv[4] = {vp.x, vp.y, vp.z, vp.w};
        #pragma unroll
        for (int j = 0; j < 4; ++j) {
            int cj = c + j;
            float m = vsum[cj] * invG;
            float var = vss[cj] * invG - m * m;
            float r = rsqrtf(var + BN_EPS);
            float a = gv[cj] * r;
            o[j] += fmaxf(fmaf(a, vv[j], btv[cj] - m * a), 0.f);
        }
    }
    uint2 pk;
    pk.x = pk2(o[0], o[1]);
    pk.y = pk2(o[2], o[3]);
    *(uint2*)(hin + base) = pk;
}

// ---------------------------------------------------------------- gather aggregation
__device__ __forceinline__ void edge_term_f(
    u32 h, f32x4v ea, f32x4v eb, const f32x2* rW, f32x2 rB, f32x2& acc)
{
    f32x2 ex = rB;
    ex = __builtin_elementwise_fma(splat2(ea.x), rW[0], ex);
    ex = __builtin_elementwise_fma(splat2(ea.y), rW[1], ex);
    ex = __builtin_elementwise_fma(splat2(ea.z), rW[2], ex);
    ex = __builtin_elementwise_fma(splat2(ea.w), rW[3], ex);
    ex = __builtin_elementwise_fma(splat2(eb.x), rW[4], ex);
    ex = __builtin_elementwise_fma(splat2(eb.y), rW[5], ex);
    ex = __builtin_elementwise_fma(splat2(eb.z), rW[6], ex);
    ex = __builtin_elementwise_fma(splat2(eb.w), rW[7], ex);
    f32x2 s = up2p(h) + ex;
    s = __builtin_elementwise_max(s, splat2(0.f));
    acc += s;
}

// flattened group stream per wave (144B inline-attr groups); node boundaries
// are wave-uniform scalar events. Block 0 also zeroes the stats buffer.
__global__ __launch_bounds__(256) void aggr_kernel(
    const int* __restrict__ grpptr, const char* __restrict__ rec,
    const float* __restrict__ Wel, const float* __restrict__ bel,
    const u16* __restrict__ hin, u16* __restrict__ z,
    const int* __restrict__ wstart, float* __restrict__ stats)
{
    const int lane = threadIdx.x & 63;
    const int cb = lane * 4;
    const int wid = __builtin_amdgcn_readfirstlane((blockIdx.x << 2) + (threadIdx.x >> 6));

    if (blockIdx.x == 0) {
        #pragma unroll
        for (int i = 0; i < 8; ++i) stats[i * 256 + threadIdx.x] = 0.f;
    }

    f32x2 rW[EFEAT];
    #pragma unroll
    for (int k = 0; k < EFEAT; ++k) {
        float2 t = *(const float2*)(Wel + k * DIM + lane * 2);
        rW[k].x = t.x; rW[k].y = t.y;
    }
    float2 tb = *(const float2*)(bel + lane * 2);
    f32x2 rB; rB.x = tb.x; rB.y = tb.y;

    const char* hinB = (const char*)hin;
    int n = wstart[wid];
    const int n1 = wstart[wid + 1];

    // leading empty nodes: z = h_in row
    while (n < n1 && grpptr[n + 1] == grpptr[n]) {
        f32x2 a0 = up2p(*(const u32*)(hinB + ((u32)n << 8) + cb));
        *(u32*)(z + ((size_t)n << 7) + lane * 2) = pk2(a0.x, a0.y);
        ++n;
    }
    if (n < n1) {
        int g = grpptr[n];
        const int gTot = grpptr[n1];
        int gEnd = grpptr[n + 1];
        f32x2 acc = up2p(*(const u32*)(hinB + ((u32)n << 8) + cb));
        const char* rb = rec + (size_t)g * 144;

        uint4 so = *(const uint4*)rb;
        u32 h0 = *(const u32*)(hinB + so.x + cb);
        u32 h1 = *(const u32*)(hinB + so.y + cb);
        u32 h2 = *(const u32*)(hinB + so.z + cb);
        u32 h3 = *(const u32*)(hinB + so.w + cb);
        f32x4v e0a = *(const f32x4v*)(rb + 16);
        f32x4v e0b = *(const f32x4v*)(rb + 32);
        f32x4v e1a = *(const f32x4v*)(rb + 48);
        f32x4v e1b = *(const f32x4v*)(rb + 64);
        f32x4v e2a = *(const f32x4v*)(rb + 80);
        f32x4v e2b = *(const f32x4v*)(rb + 96);
        f32x4v e3a = *(const f32x4v*)(rb + 112);
        f32x4v e3b = *(const f32x4v*)(rb + 128);
        uint4 soN = *(const uint4*)(rb + 144);

        #pragma unroll 2
        for (; g < gTot; ++g, rb += 144) {
            u32 i0 = *(const u32*)(hinB + soN.x + cb);
            u32 i1 = *(const u32*)(hinB + soN.y + cb);
            u32 i2 = *(const u32*)(hinB + soN.z + cb);
            u32 i3 = *(const u32*)(hinB + soN.w + cb);
            f32x4v f0a = *(const f32x4v*)(rb + 160);
            f32x4v f0b = *(const f32x4v*)(rb + 176);
            f32x4v f1a = *(const f32x4v*)(rb + 192);
            f32x4v f1b = *(const f32x4v*)(rb + 208);
            f32x4v f2a = *(const f32x4v*)(rb + 224);
            f32x4v f2b = *(const f32x4v*)(rb + 240);
            f32x4v f3a = *(const f32x4v*)(rb + 256);
            f32x4v f3b = *(const f32x4v*)(rb + 272);
            uint4 soNN = *(const uint4*)(rb + 288);
            edge_term_f(h0, e0a, e0b, rW, rB, acc);
            edge_term_f(h1, e1a, e1b, rW, rB, acc);
            edge_term_f(h2, e2a, e2b, rW, rB, acc);
            edge_term_f(h3, e3a, e3b, rW, rB, acc);
            h0 = i0; h1 = i1; h2 = i2; h3 = i3;
            e0a = f0a; e0b = f0b; e1a = f1a; e1b = f1b;
            e2a = f2a; e2b = f2b; e3a = f3a; e3b = f3b;
            soN = soNN;
            if (g + 1 == gEnd) {
                *(u32*)(z + ((size_t)n << 7) + lane * 2) = pk2(acc.x, acc.y);
                ++n;
                if (g + 1 < gTot) {
                    while (grpptr[n + 1] == grpptr[n]) {
                        f32x2 a0 = up2p(*(const u32*)(hinB + ((u32)n << 8) + cb));
                        *(u32*)(z + ((size_t)n << 7) + lane * 2) = pk2(a0.x, a0.y);
                        ++n;
                    }
                    acc = up2p(*(const u32*)(hinB + ((u32)n << 8) + cb));
                    gEnd = grpptr[n + 1];
                }
            }
        }
    }
    while (n < n1) {
        f32x2 a0 = up2p(*(const u32*)(hinB + ((u32)n << 8) + cb));
        *(u32*)(z + ((size_t)n << 7) + lane * 2) = pk2(a0.x, a0.y);
        ++n;
    }
}

// ---------------------------------------------------------------- barrier-free streaming GEMM
// B column-chunk lives in LDS (loaded once); each wave independently streams a
// 32-row A tile from global straight into MFMA A-fragments. No K-loop barriers.
__device__ __forceinline__ bf16x8_t bn_relu8(
    bf16x8_t a, int k0, const float* __restrict__ alphaS, const float* __restrict__ betaS)
{
    union { bf16x8_t v; u32 u[4]; } in, out;
    in.v = a;
    #pragma unroll
    for (int j = 0; j < 4; ++j) {
        f32x2 x = up2p(in.u[j]);
        float2 al = *(const float2*)(alphaS + k0 + j * 2);
        float2 be = *(const float2*)(betaS + k0 + j * 2);
        f32x2 av; av.x = al.x; av.y = al.y;
        f32x2 bv; bv.x = be.x; bv.y = be.y;
        f32x2 r = __builtin_elementwise_fma(x, av, bv);
        r = __builtin_elementwise_max(r, splat2(0.f));
        out.u[j] = pk2(r.x, r.y);
    }
    return out.v;
}

template <int MODE, bool CBF16, int K, int NCB>
__global__ __launch_bounds__(256) void gemm_stream_kernel(
    const u16* __restrict__ Aa,
    const float* __restrict__ sSum, const float* __restrict__ sSS,
    const float* __restrict__ gA, const float* __restrict__ btA, float invCnt,
    const u16* __restrict__ Bt,          // [Nc][K] bf16
    const float* __restrict__ bias,
    void* __restrict__ CoutV,
    float* __restrict__ outSum, float* __restrict__ outSS,
    int M, int Nc)
{
    constexpr int LDK = K + 8;
    constexpr int NT = NCB / 16;         // 16-col tiles per chunk
    constexpr int KS = K / 32;           // MFMA k-steps
    constexpr int TPR = K / 8;           // uint4 loads per B row
    constexpr int NLOAD = NCB * TPR / 256;
    __shared__ u16 Bs[NCB * LDK];
    __shared__ float alphaS[K], betaS[K];
    __shared__ float csum[NCB], css[NCB];

    const int tid = threadIdx.x;
    const int wave = tid >> 6, lane = tid & 63;
    const int quad = lane >> 4, l16 = lane & 15;
    const int col0 = blockIdx.y * NCB;

    #pragma unroll
    for (int i = tid; i < NCB; i += 256) { csum[i] = 0.f; css[i] = 0.f; }
    if (MODE == 1) {
        for (int k = tid; k < K; k += 256) {
            float m = sSum[k] * invCnt;
            float var = sSS[k] * invCnt - m * m;
            float r = rsqrtf(var + BN_EPS);
            float a = gA[k] * r;
            alphaS[k] = a;
            betaS[k] = btA[k] - m * a;
        }
    }
    #pragma unroll
    for (int it = 0; it < NLOAD; ++it) {
        int chunk = it * 256 + tid;
        int nrow = chunk / TPR;
        int k0 = (chunk % TPR) * 8;
        uint4 q = *(const uint4*)(Bt + (size_t)(col0 + nrow) * K + k0);
        *(uint4*)(Bs + nrow * LDK + k0) = q;
    }
    __syncthreads();

    const int ntile = (M + 31) >> 5;
    const int wtile = blockIdx.x * 4 + wave;
    if (wtile < ntile) {
        const int m0 = wtile * 32;
        int ra = m0 + l16;       if (ra >= M) ra = M - 1;
        int rb = m0 + 16 + l16;  if (rb >= M) rb = M - 1;
        const u16* A0 = Aa + (size_t)ra * K;
        const u16* A1 = Aa + (size_t)rb * K;

        f32x4_t acc[2][NT];
        #pragma unroll
        for (int s = 0; s < 2; ++s)
            #pragma unroll
            for (int ni = 0; ni < NT; ++ni)
                acc[s][ni] = (f32x4_t){0.f, 0.f, 0.f, 0.f};

        #pragma unroll
        for (int ks = 0; ks < KS; ++ks) {
            const int k0 = ks * 32 + quad * 8;
            bf16x8_t a0 = *(const bf16x8_t*)(A0 + k0);
            bf16x8_t a1 = *(const bf16x8_t*)(A1 + k0);
            if (MODE == 1) {
                a0 = bn_relu8(a0, k0, alphaS, betaS);
                a1 = bn_relu8(a1, k0, alphaS, betaS);
            }
            #pragma unroll
            for (int ni = 0; ni < NT; ++ni) {
                bf16x8_t b = *(const bf16x8_t*)(Bs + (ni * 16 + l16) * LDK + k0);
                acc[0][ni] = __builtin_amdgcn_mfma_f32_16x16x32_bf16(a0, b, acc[0][ni], 0, 0, 0);
                acc[1][ni] = __builtin_amdgcn_mfma_f32_16x16x32_bf16(a1, b, acc[1][ni], 0, 0, 0);
            }
        }

        u16* Cb = (u16*)CoutV;
        float* Cf = (float*)CoutV;
        #pragma unroll
        for (int ni = 0; ni < NT; ++ni) {
            int lc = ni * 16 + l16;
            int col = col0 + lc;
            float bv = bias[col];
            float s = 0.f, qs = 0.f;
            #pragma unroll
            for (int sub = 0; sub < 2; ++sub) {
                int rbase = m0 + sub * 16 + quad * 4;
                #pragma unroll
                for (int reg = 0; reg < 4; ++reg) {
                    int gr = rbase + reg;
                    if (gr < M) {
                        float o = acc[sub][ni][reg] + bv;
                        s += o;
                        qs += o * o;
                        if (CBF16) Cb[(size_t)gr * Nc + col] = f2bf(o);
                        else       Cf[(size_t)gr * Nc + col] = o;
                    }
                }
            }
            s += __shfl_xor(s, 16);  s += __shfl_xor(s, 32);
            qs += __shfl_xor(qs, 16);  qs += __shfl_xor(qs, 32);
            if (quad == 0) {
                atomicAdd(&csum[lc], s);
                atomicAdd(&css[lc], qs);
            }
        }
    }
    __syncthreads();
    #pragma unroll
    for (int i = tid; i < NCB; i += 256) {
        atomic_add_f(outSum + col0 + i, csum[i]);
        atomic_add_f(outSS + col0 + i, css[i]);
    }
}

// ---------------------------------------------------------------- fp32 GEMM (VN path, tiny M)
template <int MODE>
__global__ __launch_bounds__(256) void gemm_kernel(
    const float* __restrict__ Aa,
    const float* __restrict__ sSum, const float* __restrict__ sSS,
    const float* __restrict__ gA, const float* __restrict__ btA, float invCnt,
    const float* __restrict__ B, const float* __restrict__ bias,
    float* __restrict__ Cout, float* __restrict__ outSum, float* __restrict__ outSS,
    int M, int K, int Nc)
{
    __shared__ float As[16][68];
    __shared__ float Bs[16][64];
    __shared__ float alphaS[256], betaS[256];
    __shared__ float csum[64], css[64];

    const int tid = threadIdx.x;
    const int tx = tid & 15, ty = tid >> 4;
    const int row0 = blockIdx.x * 64, col0 = blockIdx.y * 64;

    if (tid < 64) { csum[tid] = 0.f; css[tid] = 0.f; }
    if (MODE == 1) {
        for (int k = tid; k < K; k += 256) {
            float m = sSum[k] * invCnt;
            float var = sSS[k] * invCnt - m * m;
            float r = rsqrtf(var + BN_EPS);
            float a = gA[k] * r;
            alphaS[k] = a;
            betaS[k] = btA[k] - m * a;
        }
    }
    __syncthreads();

    float acc[4][4];
    #pragma unroll
    for (int i = 0; i < 4; ++i)
        #pragma unroll
        for (int j = 0; j < 4; ++j) acc[i][j] = 0.f;

    const int lr = tid >> 2;
    const int lk = (tid & 3) * 4;
    const int bk = tid >> 4;
    const int bc = tx * 4;

    for (int kt = 0; kt < K; kt += 16) {
        int gr = row0 + lr;
        float4 va = make_float4(0.f, 0.f, 0.f, 0.f);
        if (gr < M) {
            va = *(const float4*)(Aa + (size_t)gr * K + kt + lk);
            if (MODE == 1) {
                int k0 = kt + lk;
                va.x = fmaxf(fmaf(alphaS[k0 + 0], va.x, betaS[k0 + 0]), 0.f);
                va.y = fmaxf(fmaf(alphaS[k0 + 1], va.y, betaS[k0 + 1]), 0.f);
                va.z = fmaxf(fmaf(alphaS[k0 + 2], va.z, betaS[k0 + 2]), 0.f);
                va.w = fmaxf(fmaf(alphaS[k0 + 3], va.w, betaS[k0 + 3]), 0.f);
            }
        }
        As[lk + 0][lr] = va.x;
        As[lk + 1][lr] = va.y;
        As[lk + 2][lr] = va.z;
        As[lk + 3][lr] = va.w;
        const float4 vb4 = *(const float4*)(B + (size_t)(kt + bk) * Nc + col0 + bc);
        *(float4*)&Bs[bk][bc] = vb4;
        __syncthreads();
        #pragma unroll
        for (int kk = 0; kk < 16; ++kk) {
            const float4 a4 = *(const float4*)&As[kk][ty * 4];
            const float4 b4 = *(const float4*)&Bs[kk][tx * 4];
            float av[4] = {a4.x, a4.y, a4.z, a4.w};
            float bv4[4] = {b4.x, b4.y, b4.z, b4.w};
            #pragma unroll
            for (int i = 0; i < 4; ++i)
                #pragma unroll
                for (int j = 0; j < 4; ++j)
                    acc[i][j] = fmaf(av[i], bv4[j], acc[i][j]);
        }
        __syncthreads();
    }

    const float4 bvv = *(const float4*)(bias + col0 + tx * 4);
    float bias4[4] = {bvv.x, bvv.y, bvv.z, bvv.w};
    float ps[4] = {0.f, 0.f, 0.f, 0.f};
    float pq[4] = {0.f, 0.f, 0.f, 0.f};
    #pragma unroll
    for (int i = 0; i < 4; ++i) {
        int gr = row0 + ty * 4 + i;
        if (gr < M) {
            float o[4];
            #pragma unroll
            for (int j = 0; j < 4; ++j) {
                o[j] = acc[i][j] + bias4[j];
                ps[j] += o[j];
                pq[j] += o[j] * o[j];
            }
            *(float4*)(Cout + (size_t)gr * Nc + col0 + tx * 4) = make_float4(o[0], o[1], o[2], o[3]);
        }
    }
    #pragma unroll
    for (int j = 0; j < 4; ++j) {
        atomicAdd(&csum[tx * 4 + j], ps[j]);
        atomicAdd(&css[tx * 4 + j], pq[j]);
    }
    __syncthreads();
    if (tid < 64) {
        atomic_add_f(outSum + col0 + tid, csum[tid]);
        atomic_add_f(outSS + col0 + tid, css[tid]);
    }
}

// ---------------------------------------------------------------- pooled[g] = vn[g] + segment_sum(h_in, batch)[g]
template <int VNM>
__global__ __launch_bounds__(64) void pooled_seg_kernel(
    const u16* __restrict__ hin, const int* __restrict__ batch,
    const float* __restrict__ vn_emb,
    const float* __restrict__ vnpre, const float* __restrict__ vsum, const float* __restrict__ vss,
    const float* __restrict__ gv, const float* __restrict__ btv, float invG,
    float* __restrict__ pooled)
{
    int g = blockIdx.x;
    int lane = threadIdx.x;
    int c2 = lane * 2;
    int lo = 0, hi = N_NODES;
    while (lo < hi) { int mid = (lo + hi) >> 1; if (batch[mid] < g) lo = mid + 1; else hi = mid; }
    int start = lo;
    hi = N_NODES;
    while (lo < hi) { int mid = (lo + hi) >> 1; if (batch[mid] < g + 1) lo = mid + 1; else hi = mid; }
    int end = lo;

    f32x2 acc;
    if (VNM == 0) {
        float2 w = *(const float2*)(vn_emb + c2);
        acc.x = w.x; acc.y = w.y;
    } else {
        float2 vs = *(const float2*)(vsum + c2);
        float2 vq = *(const float2*)(vss + c2);
        float2 gg = *(const float2*)(gv + c2);
        float2 bt = *(const float2*)(btv + c2);
        float2 vp = *(const float2*)(vnpre + (size_t)g * DIM + c2);
        float m0 = vs.x * invG, m1 = vs.y * invG;
        float va0 = vq.x * invG - m0 * m0, va1 = vq.y * invG - m1 * m1;
        float a0 = gg.x * rsqrtf(va0 + BN_EPS), a1 = gg.y * rsqrtf(va1 + BN_EPS);
        acc.x = fmaxf(fmaf(a0, vp.x, bt.x - m0 * a0), 0.f);
        acc.y = fmaxf(fmaf(a1, vp.y, bt.y - m1 * a1), 0.f);
    }

    const char* hinB = (const char*)hin;
    const int cb = lane * 4;
    f32x2 s0 = splat2(0.f), s1 = splat2(0.f), s2 = splat2(0.f), s3 = splat2(0.f);
    int n = start;
    for (; n + 3 < end; n += 4) {
        s0 += up2p(*(const u32*)(hinB + ((size_t)(n + 0) << 8) + cb));
        s1 += up2p(*(const u32*)(hinB + ((size_t)(n + 1) << 8) + cb));
        s2 += up2p(*(const u32*)(hinB + ((size_t)(n + 2) << 8) + cb));
        s3 += up2p(*(const u32*)(hinB + ((size_t)(n + 3) << 8) + cb));
    }
    for (; n < end; ++n) s0 += up2p(*(const u32*)(hinB + ((size_t)n << 8) + cb));
    acc += (s0 + s1) + (s2 + s3);
    *(float2*)(pooled + (size_t)g * DIM + c2) = make_float2(acc.x, acc.y);
}

// ---------------------------------------------------------------- final in-place BN on d_out (no relu)
__global__ __launch_bounds__(256) void final_bn_kernel(
    float* __restrict__ outp, const float* __restrict__ sum2, const float* __restrict__ ss2,
    const float* __restrict__ g, const float* __restrict__ b, float invN, int total4)
{
    int idx = blockIdx.x * 256 + threadIdx.x;
    if (idx >= total4) return;
    int base = idx * 4;
    int c = base & (DIM - 1);
    float4 v = *(const float4*)(outp + base);
    float o[4] = {v.x, v.y, v.z, v.w};
    #pragma unroll
    for (int j = 0; j < 4; ++j) {
        int cj = c + j;
        float m = sum2[cj] * invN;
        float var = ss2[cj] * invN - m * m;
        float r = rsqrtf(var + BN_EPS);
        float a = g[cj] * r;
        o[j] = fmaf(a, o[j], b[cj] - m * a);
    }
    *(float4*)(outp + base) = make_float4(o[0], o[1], o[2], o[3]);
}

// ---------------------------------------------------------------- launch
extern "C" void kernel_launch(void* const* d_in, const int* in_sizes, int n_in,
                              void* d_out, int out_size, void* d_ws, size_t ws_size,
                              hipStream_t stream) {
    const float* x         = (const float*)d_in[0];
    const float* edge_attr = (const float*)d_in[1];
    const float* vn_emb    = (const float*)d_in[2];
    const float* We        = (const float*)d_in[3];
    const float* be        = (const float*)d_in[4];
    const float* W1        = (const float*)d_in[5];
    const float* b1        = (const float*)d_in[6];
    const float* g1v       = (const float*)d_in[7];
    const float* bt1       = (const float*)d_in[8];
    const float* W2        = (const float*)d_in[9];
    const float* b2        = (const float*)d_in[10];
    const float* gb        = (const float*)d_in[11];
    const float* bb        = (const float*)d_in[12];
    const float* Wv1       = (const float*)d_in[13];
    const float* bv1       = (const float*)d_in[14];
    const float* gv1       = (const float*)d_in[15];
    const float* btv1      = (const float*)d_in[16];
    const float* Wv2       = (const float*)d_in[17];
    const float* bv2       = (const float*)d_in[18];
    const float* gv2       = (const float*)d_in[19];
    const float* btv2      = (const float*)d_in[20];
    const int* edge_index  = (const int*)d_in[21];
    const int* batch       = (const int*)d_in[22];
    float* outp = (float*)d_out;

    auto au = [](size_t x) { return (x + 255) & ~(size_t)255; };
    char* p = (char*)d_ws;
    u16* h_in   = (u16*)p;  p += au((size_t)(N_NODES + 1) * DIM * 2);   // +1 sentinel row
    u16* z_bf   = (u16*)p;  p += au((size_t)N_NODES * DIM * 2);
    u16* c1_bf  = (u16*)p;  p += au((size_t)N_NODES * HID * 2);
    u16* W1t    = (u16*)p;  p += au((size_t)3 * 32768 * 2);
    u16* W2t    = (u16*)p;  p += au((size_t)3 * 32768 * 2);
    float* pooled = (float*)p;  p += au((size_t)N_GRAPH * DIM * 4);
    float* tpre   = (float*)p;  p += au((size_t)N_GRAPH * HID * 4);
    float* vnpre  = (float*)p;  p += au((size_t)N_GRAPH * DIM * 4);
    float* stats  = (float*)p;  p += au(2048 * 4);
    float* sum1 = stats,        *ss1 = stats + 256;
    float* sum2 = stats + 512,  *ss2 = stats + 640;
    float* vsum1 = stats + 768, *vss1 = stats + 1024;
    float* vsum2 = stats + 1280, *vss2 = stats + 1408;
    int* grpptr = (int*)p;  p += au((size_t)(N_NODES + 1) * 4);
    int* wstart = (int*)p;  p += au((size_t)(AGGR_WAVES + 1) * 4);
    int* bsum   = (int*)p;  p += au((size_t)SCAN_BLOCKS * 4);
    char* brec  = p;        p += au((size_t)(MAX_GROUPS + 4) * 144 + 512);
    // prep-only aliases over layer-phase buffers:
    int* deg   = (int*)z_bf;                       // hist/scan only, before aggr writes z
    int* rank  = (int*)c1_bf;                      // scatter only (3.2MB)
    uint2* srec = (uint2*)(c1_bf + au((size_t)N_EDGES * 4) / 2);  // compact rec inside c1

    const float invN = 1.0f / (float)N_NODES;
    const float invG = 1.0f / (float)N_GRAPH;
    const int total4 = N_NODES * DIM / 4;
    const int nslots = (MAX_GROUPS + 4) * 4;

    // ---- one-time prep ----
    hipMemsetAsync(deg, 0, N_NODES * sizeof(int), stream);
    hist_rank_kernel<<<(N_EDGES + 255) / 256, 256, 0, stream>>>(edge_index, deg, rank);
    scan1_kernel<<<SCAN_BLOCKS, 1024, 0, stream>>>(deg, grpptr, bsum);
    scan2_kernel<<<1, 64, 0, stream>>>(bsum);
    scan3_kernel<<<SCAN_BLOCKS, 1024, 0, stream>>>(grpptr, bsum);
    padinit_kernel<<<(nslots / 2 + 255) / 256, 256, 0, stream>>>((uint4*)srec, nslots / 2, h_in);
    scatter_kernel<<<(N_EDGES + 255) / 256, 256, 0, stream>>>(
        edge_index, rank, grpptr, srec);
    expand_kernel<<<(nslots + 255) / 256, 256, 0, stream>>>(
        srec, edge_attr, brec, nslots);
    wstart_kernel<<<(AGGR_WAVES + 256) / 256, 256, 0, stream>>>(grpptr, wstart);
    wconv_kernel<<<768, 256, 0, stream>>>(W1, W2, W1t, W2t);

    const int AGGR_BLOCKS = AGGR_WAVES / 4;
    const int ntile32 = (N_NODES + 31) / 32;          // 1563
    const int gsx = (ntile32 + 3) / 4;                // 391

    for (int l = 0; l < N_LAYER; ++l) {
        if (l == 0)
            hin_kernel<false, 0><<<(total4 + 255) / 256, 256, 0, stream>>>(
                x, nullptr, nullptr, nullptr, nullptr, 0.f, batch,
                vn_emb, nullptr, nullptr, nullptr, nullptr, nullptr, 0.f,
                h_in, total4);
        else
            hin_kernel<true, 1><<<(total4 + 255) / 256, 256, 0, stream>>>(
                outp, sum2, ss2, gb + (size_t)(l - 1) * DIM, bb + (size_t)(l - 1) * DIM, invN, batch,
                nullptr, vnpre, vsum2, vss2,
                gv2 + (size_t)(l - 1) * DIM, btv2 + (size_t)(l - 1) * DIM, invG,
                h_in, total4);

        if (l == 0)
            pooled_seg_kernel<0><<<N_GRAPH, 64, 0, stream>>>(
                h_in, batch, vn_emb, nullptr, nullptr, nullptr, nullptr, nullptr, 0.f, pooled);
        else if (l < N_LAYER - 1)
            pooled_seg_kernel<1><<<N_GRAPH, 64, 0, stream>>>(
                h_in, batch, nullptr, vnpre, vsum2, vss2,
                gv2 + (size_t)(l - 1) * DIM, btv2 + (size_t)(l - 1) * DIM, invG, pooled);

        aggr_kernel<<<AGGR_BLOCKS, 256, 0, stream>>>(
            grpptr, brec, We + (size_t)l * EFEAT * DIM, be + (size_t)l * DIM,
            h_in, z_bf, wstart, stats);

        // c1 = z @ W1: M=50000, K=128, Nc=256 -> chunks of 128 cols
        dim3 g1d(gsx, HID / 128);
        gemm_stream_kernel<0, true, DIM, 128><<<g1d, 256, 0, stream>>>(
            z_bf, nullptr, nullptr, nullptr, nullptr, 0.f,
            W1t + (size_t)l * 32768, b1 + (size_t)l * HID,
            (void*)c1_bf, sum1, ss1, N_NODES, HID);

        // h = bn(c1)relu @ W2: M=50000, K=256, Nc=128 -> chunks of 64 cols
        dim3 g2d(gsx, DIM / 64);
        gemm_stream_kernel<1, false, HID, 64><<<g2d, 256, 0, stream>>>(
            c1_bf, sum1, ss1, g1v + (size_t)l * HID, bt1 + (size_t)l * HID, invN,
            W2t + (size_t)l * 32768, b2 + (size_t)l * DIM,
            (void*)outp, sum2, ss2, N_NODES, DIM);

        if (l < N_LAYER - 1) {
            dim3 g3d(N_GRAPH / 64, HID / 64);
            gemm_kernel<0><<<g3d, 256, 0, stream>>>(
                pooled, nullptr, nullptr, nullptr, nullptr, 0.f,
                Wv1 + (size_t)l * DIM * HID, bv1 + (size_t)l * HID,
                tpre, vsum1, vss1, N_GRAPH, DIM, HID);

            dim3 g4d(N_GRAPH / 64, DIM / 64);
            gemm_kernel<1><<<g4d, 256, 0, stream>>>(
                tpre, vsum1, vss1, gv1 + (size_t)l * HID, btv1 + (size_t)l * HID, invG,
                Wv2 + (size_t)l * HID * DIM, bv2 + (size_t)l * DIM,
                vnpre, vsum2, vss2, N_GRAPH, HID, DIM);
        }
    }

    final_bn_kernel<<<(total4 + 255) / 256, 256, 0, stream>>>(
        outp, sum2, ss2, gb + (size_t)2 * DIM, bb + (size_t)2 * DIM, invN, total4);
}